// Round 3
// baseline (121.422 us; speedup 1.0000x reference)
//
#include <hip/hip_runtime.h>

#define ROWS 1024
#define PTS 6144              // points per batch row (2048*3)
#define NDIH (PTS - 3)        // 6141 dihedrals per row
#define ROWF (PTS * 3)        // 18432 floats per row
#define CHUNK 3072            // dihedrals per block
#define DPT 6                 // dihedrals per thread
#define THREADS 512           // CHUNK / DPT
#define NCHUNK 2              // ceil(6141/3072)
#define ANG_PER_ROW (2 * NDIH)                // 12282
#define SFLOATS ((CHUNK + 3) * 3 + 3)         // 9228 floats = 36.9 KB, /4 = 2307
#define EPS_SHIFT 1e-8f

__global__ __launch_bounds__(THREADS) void dih_kernel(const float* __restrict__ in,
                                                      float* __restrict__ out) {
    __shared__ float s[SFLOATS];
    const int b     = blockIdx.x >> 1;     // NCHUNK == 2
    const int chunk = blockIdx.x & 1;
    const int i0    = chunk * CHUNK;
    const int t     = threadIdx.x;

    // ---- coalesced float4 global -> LDS staging ----
    const float* row = in + (size_t)b * ROWF;
    const int base = i0 * 3;                              // 0 or 9216 -> 16B aligned
    const int n4 = min(SFLOATS / 4, (ROWF - base) / 4);   // 2307 (chunk0) / 2304 (chunk1)
    const float4* g4 = (const float4*)(row + base);
    float4* s4 = (float4*)s;
    #pragma unroll
    for (int k = 0; k < 5; ++k) {
        const int idx = t + k * THREADS;
        if (idx < n4) s4[idx] = g4[idx];
    }
    __syncthreads();

    // first_three output (x[:, :3, :]) — once per row, from chunk 0
    if (chunk == 0 && t < 9)
        out[(size_t)ROWS * ANG_PER_ROW + (size_t)b * 9 + t] = s[t];

    // ---- 28-float window (points i0+6t .. i0+6t+8, +1 pad) via 7x ds_read_b128 ----
    // base byte addr = 72*t -> 16B aligned
    float w[28];
    {
        const float4* ls4 = (const float4*)(s + 18 * t);
        #pragma unroll
        for (int k = 0; k < 7; ++k) {
            const float4 v = ls4[k];
            w[4*k+0] = v.x; w[4*k+1] = v.y; w[4*k+2] = v.z; w[4*k+3] = v.w;
        }
    }

    // ---- shared edge differences e_j = x_j - x_{j+1}, j = 0..7 ----
    float ex[8], ey[8], ez[8];
    #pragma unroll
    for (int j = 0; j < 8; ++j) {
        ex[j] = w[3*j + 0] - w[3*j + 3];
        ey[j] = w[3*j + 1] - w[3*j + 4];
        ez[j] = w[3*j + 2] - w[3*j + 5];
    }

    float sv[DPT], cv[DPT];
    #pragma unroll
    for (int k = 0; k < DPT; ++k) {
        // a-b = e[k], b-c = e[k+1], c-d = e[k+2]
        const float brx = ex[k+1] + EPS_SHIFT;
        const float bry = ey[k+1] + EPS_SHIFT;
        const float brz = ez[k+1] + EPS_SHIFT;
        const float nrm2 = brx*brx + bry*bry + brz*brz;
        const float inv = rsqrtf(fmaxf(nrm2, 1e-24f));   // 1/clip(|bc|,1e-12)
        const float ux = brx * inv, uy = bry * inv, uz = brz * inv;

        // n1 = cross(a-b, u)
        const float n1x = ey[k]*uz - ez[k]*uy;
        const float n1y = ez[k]*ux - ex[k]*uz;
        const float n1z = ex[k]*uy - ey[k]*ux;
        // n2 = cross(u, c-d)
        const float n2x = uy*ez[k+2] - uz*ey[k+2];
        const float n2y = uz*ex[k+2] - ux*ez[k+2];
        const float n2z = ux*ey[k+2] - uy*ex[k+2];

        const float xc = n1x*n2x + n1y*n2y + n1z*n2z;
        // m = cross(n1, u)
        const float mx = n1y*uz - n1z*uy;
        const float my = n1z*ux - n1x*uz;
        const float mz = n1x*uy - n1y*ux;
        const float yc = mx*n2x + my*n2y + mz*n2z;

        // sin/cos of atan2(yc, xc+eps) without transcendentals
        const float xz = xc + EPS_SHIFT;
        const float r2 = yc*yc + xz*xz;
        const float rinv = rsqrtf(fmaxf(r2, 1e-30f));
        sv[k] = (r2 > 0.0f) ? yc * rinv : 0.0f;
        cv[k] = (r2 > 0.0f) ? xz * rinv : 1.0f;
    }

    // ---- stores ----
    const int i = i0 + DPT * t;                 // first dihedral of this thread
    const size_t obase = (size_t)b * ANG_PER_ROW;
    if (i + DPT - 1 < NDIH) {
        // sin block: base even -> 3x float2
        float2* so = (float2*)(out + obase + i);
        so[0] = make_float2(sv[0], sv[1]);
        so[1] = make_float2(sv[2], sv[3]);
        so[2] = make_float2(sv[4], sv[5]);
        // cos block base odd (NDIH=6141) -> scalar stores
        float* co = out + obase + NDIH + i;
        #pragma unroll
        for (int k = 0; k < DPT; ++k) co[k] = cv[k];
    } else {
        #pragma unroll
        for (int k = 0; k < DPT; ++k) {
            if (i + k < NDIH) {
                out[obase + i + k]        = sv[k];
                out[obase + NDIH + i + k] = cv[k];
            }
        }
    }
}

extern "C" void kernel_launch(void* const* d_in, const int* in_sizes, int n_in,
                              void* d_out, int out_size, void* d_ws, size_t ws_size,
                              hipStream_t stream) {
    const float* in = (const float*)d_in[0];
    float* out = (float*)d_out;
    dih_kernel<<<dim3(ROWS * NCHUNK), dim3(THREADS), 0, stream>>>(in, out);
}

// Round 4
// 120.121 us; speedup vs baseline: 1.0108x; 1.0108x over previous
//
#include <hip/hip_runtime.h>

#define ROWS 1024
#define PTS 6144              // points per batch row (2048*3)
#define NDIH (PTS - 3)        // 6141 dihedrals per row
#define ROWF (PTS * 3)        // 18432 floats per row
#define CHUNK 1024            // dihedrals per block
#define DPT 4                 // dihedrals per thread
#define THREADS 256           // CHUNK / DPT
#define NCHUNK 6              // ceil(6141/1024)
#define ANG_PER_ROW (2 * NDIH)                // 12282
#define SFLOATS ((CHUNK + 3) * 3 + 3)         // 3084 floats = 12.3 KB
#define EPS_SHIFT 1e-8f

__global__ __launch_bounds__(THREADS) void dih_kernel(const float* __restrict__ in,
                                                      float* __restrict__ out) {
    __shared__ float s[SFLOATS];   // input stage, then reused as output stage (2048 floats)
    const int b     = blockIdx.x / NCHUNK;
    const int chunk = blockIdx.x % NCHUNK;
    const int i0    = chunk * CHUNK;
    const int t     = threadIdx.x;

    // ---- coalesced float4 global -> LDS staging ----
    const float* row = in + (size_t)b * ROWF;
    const int base = i0 * 3;                              // multiple of 3072 -> 16B aligned
    const int n4 = min(SFLOATS / 4, (ROWF - base) / 4);   // 771 normal, 768 last chunk
    const float4* g4 = (const float4*)(row + base);
    float4* s4 = (float4*)s;
    for (int k = t; k < n4; k += THREADS) s4[k] = g4[k];
    __syncthreads();

    // first_three output (x[:, :3, :]) — once per row, from chunk 0
    if (chunk == 0 && t < 9)
        out[(size_t)ROWS * ANG_PER_ROW + (size_t)b * 9 + t] = s[t];

    // ---- 21-float window (points i0+4t .. i0+4t+6) via 5x ds_read_b128 + 1 ----
    float w[21];
    {
        const float4* ls4 = (const float4*)(s + 12 * t);
        float4 v0 = ls4[0], v1 = ls4[1], v2 = ls4[2], v3 = ls4[3], v4 = ls4[4];
        w[0]=v0.x;  w[1]=v0.y;  w[2]=v0.z;  w[3]=v0.w;
        w[4]=v1.x;  w[5]=v1.y;  w[6]=v1.z;  w[7]=v1.w;
        w[8]=v2.x;  w[9]=v2.y;  w[10]=v2.z; w[11]=v2.w;
        w[12]=v3.x; w[13]=v3.y; w[14]=v3.z; w[15]=v3.w;
        w[16]=v4.x; w[17]=v4.y; w[18]=v4.z; w[19]=v4.w;
        w[20]=s[12 * t + 20];
    }

    // ---- shared edge differences e_j = x_j - x_{j+1}, j = 0..5 ----
    float ex[6], ey[6], ez[6];
    #pragma unroll
    for (int j = 0; j < 6; ++j) {
        ex[j] = w[3*j + 0] - w[3*j + 3];
        ey[j] = w[3*j + 1] - w[3*j + 4];
        ez[j] = w[3*j + 2] - w[3*j + 5];
    }

    float sv[DPT], cv[DPT];
    #pragma unroll
    for (int k = 0; k < DPT; ++k) {
        const float brx = ex[k+1] + EPS_SHIFT;
        const float bry = ey[k+1] + EPS_SHIFT;
        const float brz = ez[k+1] + EPS_SHIFT;
        const float nrm2 = brx*brx + bry*bry + brz*brz;
        const float inv = rsqrtf(fmaxf(nrm2, 1e-24f));   // 1/clip(|bc|,1e-12)
        const float ux = brx * inv, uy = bry * inv, uz = brz * inv;

        // n1 = cross(a-b, u)
        const float n1x = ey[k]*uz - ez[k]*uy;
        const float n1y = ez[k]*ux - ex[k]*uz;
        const float n1z = ex[k]*uy - ey[k]*ux;
        // n2 = cross(u, c-d)
        const float n2x = uy*ez[k+2] - uz*ey[k+2];
        const float n2y = uz*ex[k+2] - ux*ez[k+2];
        const float n2z = ux*ey[k+2] - uy*ex[k+2];

        const float xc = n1x*n2x + n1y*n2y + n1z*n2z;
        // m = cross(n1, u)
        const float mx = n1y*uz - n1z*uy;
        const float my = n1z*ux - n1x*uz;
        const float mz = n1x*uy - n1y*ux;
        const float yc = mx*n2x + my*n2y + mz*n2z;

        const float xz = xc + EPS_SHIFT;
        const float r2 = yc*yc + xz*xz;
        const float rinv = rsqrtf(fmaxf(r2, 1e-30f));
        sv[k] = (r2 > 0.0f) ? yc * rinv : 0.0f;
        cv[k] = (r2 > 0.0f) ? xz * rinv : 1.0f;
    }

    // ---- transpose outputs through LDS, then fully-packed global stores ----
    __syncthreads();   // all input reads done; safe to overwrite s
    ((float4*)s)[t]           = make_float4(sv[0], sv[1], sv[2], sv[3]);   // s[4t..4t+3]
    ((float4*)(s + CHUNK))[t] = make_float4(cv[0], cv[1], cv[2], cv[3]);   // s[1024+4t..]
    __syncthreads();

    const size_t obase = (size_t)b * ANG_PER_ROW;
    const int valid = min(CHUNK, NDIH - i0);     // 1024, or 1021 for last chunk
    float* so = out + obase + i0;                // sin destination
    float* co = out + obase + NDIH + i0;         // cos destination
    #pragma unroll
    for (int k = 0; k < 4; ++k) {
        const int j = k * THREADS + t;           // consecutive addresses across lanes
        if (j < valid) {
            so[j] = s[j];
            co[j] = s[CHUNK + j];
        }
    }
}

extern "C" void kernel_launch(void* const* d_in, const int* in_sizes, int n_in,
                              void* d_out, int out_size, void* d_ws, size_t ws_size,
                              hipStream_t stream) {
    const float* in = (const float*)d_in[0];
    float* out = (float*)d_out;
    dih_kernel<<<dim3(ROWS * NCHUNK), dim3(THREADS), 0, stream>>>(in, out);
}